// Round 11
// baseline (700.440 us; speedup 1.0000x reference)
//
#include <hip/hip_runtime.h>
#include <hip/hip_bf16.h>

#define N_NODES 100000
#define N_EDGES 1600000
#define N_EL    200000
// D_IN = D_HID = 128; layer-3 output D = 64. f32 inputs, int32 indices, f32 output.
// Round 11: GEMM W staged in LDS as packed bf16 (32/16 KB instead of 64/32 KB f32).
// Round-10 counters: LDS 64KB -> 2 blocks/CU -> occ 18%, VALU 37% (latency-starved).
// Halving LDS -> 5 blocks/CU. W-bf16 rounding adds ~2^-9 rel err (budget 1.55e-2).

#define NB_SCAN ((N_NODES + 255) / 256)   // 391

typedef unsigned int uint32;
typedef unsigned short ushort16;

static __device__ __forceinline__ ushort16 f2bf(float f) {
    uint32 u = __float_as_uint(f);
    u += 0x7fffu + ((u >> 16) & 1u);      // RNE
    return (ushort16)(u >> 16);
}
static __device__ __forceinline__ float bf_lo(uint32 p) { return __uint_as_float(p << 16); }
static __device__ __forceinline__ float bf_hi(uint32 p) { return __uint_as_float(p & 0xffff0000u); }
static __device__ __forceinline__ float bf2f(ushort16 h) { return __uint_as_float((uint32)h << 16); }

// ---------------- pass 1: rank + histogram in one atomic sweep ----------------
__global__ void k_rank(const int* __restrict__ dst, int* __restrict__ cursor,
                       int* __restrict__ r) {
    int e = blockIdx.x * blockDim.x + threadIdx.x;
    if (e < N_EDGES) r[e] = atomicAdd(&cursor[dst[e]], 1);
}

// ---------------- scan pass 1 (+ dinv); deg comes from cursor ----------------
__global__ void k_scan1(const int* __restrict__ deg, int* __restrict__ rowptr,
                        int* __restrict__ bsum, float* __restrict__ dinv) {
    __shared__ int s[256];
    int t = threadIdx.x;
    int i = blockIdx.x * 256 + t;
    int v = (i < N_NODES) ? deg[i] : 0;
    if (i < N_NODES) dinv[i] = 1.0f / sqrtf((float)(v + 1));   // +1 self-loop
    s[t] = v;
    __syncthreads();
    for (int off = 1; off < 256; off <<= 1) {
        int u = (t >= off) ? s[t - off] : 0;
        __syncthreads();
        s[t] += u;
        __syncthreads();
    }
    if (i < N_NODES) rowptr[i] = s[t] - v;          // exclusive, local
    if (t == 255) bsum[blockIdx.x] = s[255];
}

__global__ void k_scan2(const int* __restrict__ bsum, int* __restrict__ boff) {
    __shared__ int s[512];
    int t = threadIdx.x;
    int v = (t < NB_SCAN) ? bsum[t] : 0;
    s[t] = v;
    __syncthreads();
    for (int off = 1; off < 512; off <<= 1) {
        int u = (t >= off) ? s[t - off] : 0;
        __syncthreads();
        s[t] += u;
        __syncthreads();
    }
    if (t < NB_SCAN) boff[t] = s[t] - v;            // exclusive
    if (t == NB_SCAN - 1) boff[NB_SCAN] = s[t];     // total
}

__global__ void k_scan3(int* __restrict__ rowptr, const int* __restrict__ boff) {
    int i = blockIdx.x * 256 + threadIdx.x;
    if (i < N_NODES) rowptr[i] += boff[blockIdx.x];
    if (i == 0) rowptr[N_NODES] = boff[NB_SCAN];
}

// ---------------- pass 2: atomic-free CSR fill ----------------
__global__ void k_fill2(const int* __restrict__ src, const int* __restrict__ dst,
                        const int* __restrict__ rowptr, const int* __restrict__ r,
                        int* __restrict__ col) {
    int e = blockIdx.x * blockDim.x + threadIdx.x;
    if (e >= N_EDGES) return;
    int pos = rowptr[dst[e]] + r[e];
    __builtin_nontemporal_store(src[e], &col[pos]);
}

// ---------------- GEMM: C[n,:] = bf16( dinv[n] * (A[n,:128] @ W[128,D]) ) ----------------
// W staged in LDS as packed bf16 (uint2 = 4 cols). 64 nodes/block, NPT x 4 per thread.
template <int D>
__global__ __launch_bounds__(256, 5) void k_gemm_lds(const float* __restrict__ A,
        const float* __restrict__ W, const float* __restrict__ dinv,
        ushort16* __restrict__ C) {
    constexpr int CG = D / 4;        // col groups: 32 (D=128) or 16 (D=64)
    constexpr int NG = 256 / CG;     // node groups
    constexpr int NPT = 64 / NG;     // nodes per thread
    __shared__ uint2 sW2[128 * CG];  // bf16x4 per entry: 32 KB (D=128) / 16 KB (D=64)

    int tid = threadIdx.x;
    int cg = tid % CG;
    int ng = tid / CG;
    int n0 = blockIdx.x * 64;

    const float4* W4 = (const float4*)W;
    for (int i = tid; i < 128 * CG; i += 256) {
        float4 w = W4[i];
        uint2 pk;
        pk.x = (uint32)f2bf(w.x) | ((uint32)f2bf(w.y) << 16);
        pk.y = (uint32)f2bf(w.z) | ((uint32)f2bf(w.w) << 16);
        sW2[i] = pk;
    }
    __syncthreads();

    float4 acc[NPT];
#pragma unroll
    for (int i = 0; i < NPT; ++i) acc[i] = make_float4(0.f, 0.f, 0.f, 0.f);

    const float4* A4 = (const float4*)A;

    for (int k4 = 0; k4 < 32; ++k4) {
        float4 av[NPT];
#pragma unroll
        for (int i = 0; i < NPT; ++i) {
            int n = n0 + ng * NPT + i;
            n = min(n, N_NODES - 1);
            av[i] = A4[(size_t)n * 32 + k4];
        }
        uint2 q0 = sW2[(k4 * 4 + 0) * CG + cg];
        uint2 q1 = sW2[(k4 * 4 + 1) * CG + cg];
        uint2 q2 = sW2[(k4 * 4 + 2) * CG + cg];
        uint2 q3 = sW2[(k4 * 4 + 3) * CG + cg];
        float4 w0 = make_float4(bf_lo(q0.x), bf_hi(q0.x), bf_lo(q0.y), bf_hi(q0.y));
        float4 w1 = make_float4(bf_lo(q1.x), bf_hi(q1.x), bf_lo(q1.y), bf_hi(q1.y));
        float4 w2 = make_float4(bf_lo(q2.x), bf_hi(q2.x), bf_lo(q2.y), bf_hi(q2.y));
        float4 w3 = make_float4(bf_lo(q3.x), bf_hi(q3.x), bf_lo(q3.y), bf_hi(q3.y));
#pragma unroll
        for (int i = 0; i < NPT; ++i) {
            acc[i].x = fmaf(av[i].x, w0.x, acc[i].x);
            acc[i].y = fmaf(av[i].x, w0.y, acc[i].y);
            acc[i].z = fmaf(av[i].x, w0.z, acc[i].z);
            acc[i].w = fmaf(av[i].x, w0.w, acc[i].w);
            acc[i].x = fmaf(av[i].y, w1.x, acc[i].x);
            acc[i].y = fmaf(av[i].y, w1.y, acc[i].y);
            acc[i].z = fmaf(av[i].y, w1.z, acc[i].z);
            acc[i].w = fmaf(av[i].y, w1.w, acc[i].w);
            acc[i].x = fmaf(av[i].z, w2.x, acc[i].x);
            acc[i].y = fmaf(av[i].z, w2.y, acc[i].y);
            acc[i].z = fmaf(av[i].z, w2.z, acc[i].z);
            acc[i].w = fmaf(av[i].z, w2.w, acc[i].w);
            acc[i].x = fmaf(av[i].w, w3.x, acc[i].x);
            acc[i].y = fmaf(av[i].w, w3.y, acc[i].y);
            acc[i].z = fmaf(av[i].w, w3.z, acc[i].z);
            acc[i].w = fmaf(av[i].w, w3.w, acc[i].w);
        }
    }

#pragma unroll
    for (int i = 0; i < NPT; ++i) {
        int n = n0 + ng * NPT + i;
        if (n < N_NODES) {
            float di = dinv[n];
            float4 o = acc[i];
            uint32 p0 = (uint32)f2bf(o.x * di) | ((uint32)f2bf(o.y * di) << 16);
            uint32 p1 = (uint32)f2bf(o.z * di) | ((uint32)f2bf(o.w * di) << 16);
            uint2 pk; pk.x = p0; pk.y = p1;
            ((uint2*)C)[(size_t)n * (CG) + cg] = pk;
        }
    }
}

// ---------------- gather, D=128: one wave/node, bf16x2/lane, 8x unroll ----------------
template <bool RELU>
__global__ void k_gather128(const int* __restrict__ rowptr, const int* __restrict__ col,
                            const float* __restrict__ dinv, const uint32* __restrict__ t,
                            const float* __restrict__ b, float* __restrict__ outbuf) {
    unsigned wid = (blockIdx.x * blockDim.x + threadIdx.x) >> 6;
    int lane = threadIdx.x & 63;
    if (wid >= N_NODES) return;
    int beg = rowptr[wid], end = rowptr[wid + 1];
    uint32 p = t[(size_t)wid * 64 + lane];
    float ax = bf_lo(p), ay = bf_hi(p);
    int j = beg;
    for (; j + 8 <= end; j += 8) {
        int s0 = col[j], s1 = col[j+1], s2 = col[j+2], s3 = col[j+3];
        int s4 = col[j+4], s5 = col[j+5], s6 = col[j+6], s7 = col[j+7];
        uint32 v0 = t[(size_t)s0 * 64 + lane];
        uint32 v1 = t[(size_t)s1 * 64 + lane];
        uint32 v2 = t[(size_t)s2 * 64 + lane];
        uint32 v3 = t[(size_t)s3 * 64 + lane];
        uint32 v4 = t[(size_t)s4 * 64 + lane];
        uint32 v5 = t[(size_t)s5 * 64 + lane];
        uint32 v6 = t[(size_t)s6 * 64 + lane];
        uint32 v7 = t[(size_t)s7 * 64 + lane];
        ax += (bf_lo(v0) + bf_lo(v1)) + (bf_lo(v2) + bf_lo(v3))
            + ((bf_lo(v4) + bf_lo(v5)) + (bf_lo(v6) + bf_lo(v7)));
        ay += (bf_hi(v0) + bf_hi(v1)) + (bf_hi(v2) + bf_hi(v3))
            + ((bf_hi(v4) + bf_hi(v5)) + (bf_hi(v6) + bf_hi(v7)));
    }
    for (; j + 4 <= end; j += 4) {
        int s0 = col[j], s1 = col[j+1], s2 = col[j+2], s3 = col[j+3];
        uint32 v0 = t[(size_t)s0 * 64 + lane];
        uint32 v1 = t[(size_t)s1 * 64 + lane];
        uint32 v2 = t[(size_t)s2 * 64 + lane];
        uint32 v3 = t[(size_t)s3 * 64 + lane];
        ax += (bf_lo(v0) + bf_lo(v1)) + (bf_lo(v2) + bf_lo(v3));
        ay += (bf_hi(v0) + bf_hi(v1)) + (bf_hi(v2) + bf_hi(v3));
    }
    for (; j < end; ++j) {
        uint32 v = t[(size_t)col[j] * 64 + lane];
        ax += bf_lo(v); ay += bf_hi(v);
    }
    float di = dinv[wid];
    float2 bb = ((const float2*)b)[lane];
    float ox = di * ax + bb.x;
    float oy = di * ay + bb.y;
    if (RELU) { ox = fmaxf(ox, 0.f); oy = fmaxf(oy, 0.f); }
    ((float2*)outbuf)[(size_t)wid * 64 + lane] = make_float2(ox, oy);
}

// ---------------- gather, D=64 ----------------
template <bool RELU>
__global__ void k_gather64(const int* __restrict__ rowptr, const int* __restrict__ col,
                           const float* __restrict__ dinv, const ushort16* __restrict__ t,
                           const float* __restrict__ b, float* __restrict__ outbuf) {
    unsigned wid = (blockIdx.x * blockDim.x + threadIdx.x) >> 6;
    int lane = threadIdx.x & 63;
    if (wid >= N_NODES) return;
    int beg = rowptr[wid], end = rowptr[wid + 1];
    float acc = bf2f(t[(size_t)wid * 64 + lane]);
    int j = beg;
    for (; j + 8 <= end; j += 8) {
        int s0 = col[j], s1 = col[j+1], s2 = col[j+2], s3 = col[j+3];
        int s4 = col[j+4], s5 = col[j+5], s6 = col[j+6], s7 = col[j+7];
        float v0 = bf2f(t[(size_t)s0 * 64 + lane]);
        float v1 = bf2f(t[(size_t)s1 * 64 + lane]);
        float v2 = bf2f(t[(size_t)s2 * 64 + lane]);
        float v3 = bf2f(t[(size_t)s3 * 64 + lane]);
        float v4 = bf2f(t[(size_t)s4 * 64 + lane]);
        float v5 = bf2f(t[(size_t)s5 * 64 + lane]);
        float v6 = bf2f(t[(size_t)s6 * 64 + lane]);
        float v7 = bf2f(t[(size_t)s7 * 64 + lane]);
        acc += (v0 + v1) + (v2 + v3) + ((v4 + v5) + (v6 + v7));
    }
    for (; j + 4 <= end; j += 4) {
        int s0 = col[j], s1 = col[j+1], s2 = col[j+2], s3 = col[j+3];
        acc += (bf2f(t[(size_t)s0 * 64 + lane]) + bf2f(t[(size_t)s1 * 64 + lane]))
             + (bf2f(t[(size_t)s2 * 64 + lane]) + bf2f(t[(size_t)s3 * 64 + lane]));
    }
    for (; j < end; ++j) acc += bf2f(t[(size_t)col[j] * 64 + lane]);
    float o = dinv[wid] * acc + b[lane];
    if (RELU) o = fmaxf(o, 0.f);
    outbuf[(size_t)wid * 64 + lane] = o;
}

// ---------------- decode ----------------
__global__ void k_decode(const int* __restrict__ eli, const float* __restrict__ z,
                         float* __restrict__ out) {
    int e = blockIdx.x * blockDim.x + threadIdx.x;
    if (e >= N_EL) return;
    int a = eli[e];
    int b = eli[N_EL + e];
    const float4* za = (const float4*)(z + (size_t)a * 64);
    const float4* zb = (const float4*)(z + (size_t)b * 64);
    float acc = 0.0f;
#pragma unroll
    for (int i = 0; i < 16; ++i) {
        float4 x = za[i], y = zb[i];
        acc += x.x * y.x + x.y * y.y + x.z * y.z + x.w * y.w;
    }
    out[e] = acc;
}

extern "C" void kernel_launch(void* const* d_in, const int* in_sizes, int n_in,
                              void* d_out, int out_size, void* d_ws, size_t ws_size,
                              hipStream_t stream) {
    const float* x   = (const float*)d_in[0];
    const int*   ei  = (const int*)d_in[1];
    const int*   eli = (const int*)d_in[2];
    const float* W1  = (const float*)d_in[3];
    const float* b1  = (const float*)d_in[4];
    const float* W2  = (const float*)d_in[5];
    const float* b2  = (const float*)d_in[6];
    const float* W3  = (const float*)d_in[7];
    const float* b3  = (const float*)d_in[8];
    float* out = (float*)d_out;

    const int* srcA = ei;
    const int* dstA = ei + N_EDGES;

    // workspace layout (bytes) — non-overlapping (verified round 10):
    char* ws = (char*)d_ws;
    float*    dinv   = (float*)   (ws + 0);
    int*      cursor = (int*)     (ws + (512u << 10));
    int*      rowptr = (int*)     (ws + (1024u << 10));
    int*      bsum   = (int*)     (ws + (1888u << 10));
    int*      boff   = (int*)     (ws + (1896u << 10));
    int*      col    = (int*)     (ws + (2048u << 10));
    int*      r      = (int*)     (ws + (9u << 20));
    ushort16* t      = (ushort16*)(ws + (16u << 20));
    float*    agg    = (float*)   (ws + (48u << 20));

    const int B = 256;
    const int gE  = (N_EDGES + B - 1) / B;
    const int gG  = (N_NODES * 64 + B - 1) / B;
    const int gT  = (N_NODES + 63) / 64;
    const int gEL = (N_EL + B - 1) / B;

    // ---- CSR build (single atomic pass) ----
    hipMemsetAsync(cursor, 0, N_NODES * sizeof(int), stream);
    k_rank<<<gE, B, 0, stream>>>(dstA, cursor, r);
    k_scan1<<<NB_SCAN, 256, 0, stream>>>(cursor, rowptr, bsum, dinv);
    k_scan2<<<1, 512, 0, stream>>>(bsum, boff);
    k_scan3<<<NB_SCAN, 256, 0, stream>>>(rowptr, boff);
    k_fill2<<<gE, B, 0, stream>>>(srcA, dstA, rowptr, r, col);

    // ---- layer 1 ----
    k_gemm_lds<128><<<gT, B, 0, stream>>>(x, W1, dinv, t);
    k_gather128<true><<<gG, B, 0, stream>>>(rowptr, col, dinv, (const uint32*)t, b1, agg);
    // ---- layer 2 ----
    k_gemm_lds<128><<<gT, B, 0, stream>>>(agg, W2, dinv, t);
    k_gather128<true><<<gG, B, 0, stream>>>(rowptr, col, dinv, (const uint32*)t, b2, agg);
    // ---- layer 3 ----
    k_gemm_lds<64><<<gT, B, 0, stream>>>(agg, W3, dinv, t);
    k_gather64<false><<<gG, B, 0, stream>>>(rowptr, col, dinv, t, b3, agg);

    // ---- decode ----
    k_decode<<<gEL, B, 0, stream>>>(eli, agg, out);
}

// Round 12
// 622.522 us; speedup vs baseline: 1.1252x; 1.1252x over previous
//
#include <hip/hip_runtime.h>
#include <hip/hip_bf16.h>

#define N_NODES 100000
#define N_EDGES 1600000
#define N_EL    200000
// D_IN = D_HID = 128; layer-3 output D = 64. f32 inputs, int32 indices, f32 output.
// Round 12: keep bf16 W in LDS (32/16 KB), relax launch_bounds (256,5)->(256,4).
// Round-11 regression root cause: min-waves=5 capped VGPR at ~102 -> allocator
// spilled acc/av arrays to scratch (VGPR 88->48, WRITE_SIZE 25->55 MB). At
// (256,4) the natural ~88 VGPR fits; LDS 32KB allows 5 blocks/CU.

#define NB_SCAN ((N_NODES + 255) / 256)   // 391

typedef unsigned int uint32;
typedef unsigned short ushort16;

static __device__ __forceinline__ ushort16 f2bf(float f) {
    uint32 u = __float_as_uint(f);
    u += 0x7fffu + ((u >> 16) & 1u);      // RNE
    return (ushort16)(u >> 16);
}
static __device__ __forceinline__ float bf_lo(uint32 p) { return __uint_as_float(p << 16); }
static __device__ __forceinline__ float bf_hi(uint32 p) { return __uint_as_float(p & 0xffff0000u); }
static __device__ __forceinline__ float bf2f(ushort16 h) { return __uint_as_float((uint32)h << 16); }

// ---------------- pass 1: rank + histogram in one atomic sweep ----------------
__global__ void k_rank(const int* __restrict__ dst, int* __restrict__ cursor,
                       int* __restrict__ r) {
    int e = blockIdx.x * blockDim.x + threadIdx.x;
    if (e < N_EDGES) r[e] = atomicAdd(&cursor[dst[e]], 1);
}

// ---------------- scan pass 1 (+ dinv); deg comes from cursor ----------------
__global__ void k_scan1(const int* __restrict__ deg, int* __restrict__ rowptr,
                        int* __restrict__ bsum, float* __restrict__ dinv) {
    __shared__ int s[256];
    int t = threadIdx.x;
    int i = blockIdx.x * 256 + t;
    int v = (i < N_NODES) ? deg[i] : 0;
    if (i < N_NODES) dinv[i] = 1.0f / sqrtf((float)(v + 1));   // +1 self-loop
    s[t] = v;
    __syncthreads();
    for (int off = 1; off < 256; off <<= 1) {
        int u = (t >= off) ? s[t - off] : 0;
        __syncthreads();
        s[t] += u;
        __syncthreads();
    }
    if (i < N_NODES) rowptr[i] = s[t] - v;          // exclusive, local
    if (t == 255) bsum[blockIdx.x] = s[255];
}

__global__ void k_scan2(const int* __restrict__ bsum, int* __restrict__ boff) {
    __shared__ int s[512];
    int t = threadIdx.x;
    int v = (t < NB_SCAN) ? bsum[t] : 0;
    s[t] = v;
    __syncthreads();
    for (int off = 1; off < 512; off <<= 1) {
        int u = (t >= off) ? s[t - off] : 0;
        __syncthreads();
        s[t] += u;
        __syncthreads();
    }
    if (t < NB_SCAN) boff[t] = s[t] - v;            // exclusive
    if (t == NB_SCAN - 1) boff[NB_SCAN] = s[t];     // total
}

__global__ void k_scan3(int* __restrict__ rowptr, const int* __restrict__ boff) {
    int i = blockIdx.x * 256 + threadIdx.x;
    if (i < N_NODES) rowptr[i] += boff[blockIdx.x];
    if (i == 0) rowptr[N_NODES] = boff[NB_SCAN];
}

// ---------------- pass 2: atomic-free CSR fill ----------------
__global__ void k_fill2(const int* __restrict__ src, const int* __restrict__ dst,
                        const int* __restrict__ rowptr, const int* __restrict__ r,
                        int* __restrict__ col) {
    int e = blockIdx.x * blockDim.x + threadIdx.x;
    if (e >= N_EDGES) return;
    int pos = rowptr[dst[e]] + r[e];
    __builtin_nontemporal_store(src[e], &col[pos]);
}

// ---------------- GEMM: C[n,:] = bf16( dinv[n] * (A[n,:128] @ W[128,D]) ) ----------------
// W staged in LDS as packed bf16 (uint2 = 4 cols). 64 nodes/block, NPT x 4 per thread.
template <int D>
__global__ __launch_bounds__(256, 4) void k_gemm_lds(const float* __restrict__ A,
        const float* __restrict__ W, const float* __restrict__ dinv,
        ushort16* __restrict__ C) {
    constexpr int CG = D / 4;        // col groups: 32 (D=128) or 16 (D=64)
    constexpr int NG = 256 / CG;     // node groups
    constexpr int NPT = 64 / NG;     // nodes per thread
    __shared__ uint2 sW2[128 * CG];  // bf16x4 per entry: 32 KB (D=128) / 16 KB (D=64)

    int tid = threadIdx.x;
    int cg = tid % CG;
    int ng = tid / CG;
    int n0 = blockIdx.x * 64;

    const float4* W4 = (const float4*)W;
    for (int i = tid; i < 128 * CG; i += 256) {
        float4 w = W4[i];
        uint2 pk;
        pk.x = (uint32)f2bf(w.x) | ((uint32)f2bf(w.y) << 16);
        pk.y = (uint32)f2bf(w.z) | ((uint32)f2bf(w.w) << 16);
        sW2[i] = pk;
    }
    __syncthreads();

    float4 acc[NPT];
#pragma unroll
    for (int i = 0; i < NPT; ++i) acc[i] = make_float4(0.f, 0.f, 0.f, 0.f);

    const float4* A4 = (const float4*)A;

    for (int k4 = 0; k4 < 32; ++k4) {
        float4 av[NPT];
#pragma unroll
        for (int i = 0; i < NPT; ++i) {
            int n = n0 + ng * NPT + i;
            n = min(n, N_NODES - 1);
            av[i] = A4[(size_t)n * 32 + k4];
        }
        uint2 q0 = sW2[(k4 * 4 + 0) * CG + cg];
        uint2 q1 = sW2[(k4 * 4 + 1) * CG + cg];
        uint2 q2 = sW2[(k4 * 4 + 2) * CG + cg];
        uint2 q3 = sW2[(k4 * 4 + 3) * CG + cg];
        float4 w0 = make_float4(bf_lo(q0.x), bf_hi(q0.x), bf_lo(q0.y), bf_hi(q0.y));
        float4 w1 = make_float4(bf_lo(q1.x), bf_hi(q1.x), bf_lo(q1.y), bf_hi(q1.y));
        float4 w2 = make_float4(bf_lo(q2.x), bf_hi(q2.x), bf_lo(q2.y), bf_hi(q2.y));
        float4 w3 = make_float4(bf_lo(q3.x), bf_hi(q3.x), bf_lo(q3.y), bf_hi(q3.y));
#pragma unroll
        for (int i = 0; i < NPT; ++i) {
            acc[i].x = fmaf(av[i].x, w0.x, acc[i].x);
            acc[i].y = fmaf(av[i].x, w0.y, acc[i].y);
            acc[i].z = fmaf(av[i].x, w0.z, acc[i].z);
            acc[i].w = fmaf(av[i].x, w0.w, acc[i].w);
            acc[i].x = fmaf(av[i].y, w1.x, acc[i].x);
            acc[i].y = fmaf(av[i].y, w1.y, acc[i].y);
            acc[i].z = fmaf(av[i].y, w1.z, acc[i].z);
            acc[i].w = fmaf(av[i].y, w1.w, acc[i].w);
            acc[i].x = fmaf(av[i].z, w2.x, acc[i].x);
            acc[i].y = fmaf(av[i].z, w2.y, acc[i].y);
            acc[i].z = fmaf(av[i].z, w2.z, acc[i].z);
            acc[i].w = fmaf(av[i].z, w2.w, acc[i].w);
            acc[i].x = fmaf(av[i].w, w3.x, acc[i].x);
            acc[i].y = fmaf(av[i].w, w3.y, acc[i].y);
            acc[i].z = fmaf(av[i].w, w3.z, acc[i].z);
            acc[i].w = fmaf(av[i].w, w3.w, acc[i].w);
        }
    }

#pragma unroll
    for (int i = 0; i < NPT; ++i) {
        int n = n0 + ng * NPT + i;
        if (n < N_NODES) {
            float di = dinv[n];
            float4 o = acc[i];
            uint32 p0 = (uint32)f2bf(o.x * di) | ((uint32)f2bf(o.y * di) << 16);
            uint32 p1 = (uint32)f2bf(o.z * di) | ((uint32)f2bf(o.w * di) << 16);
            uint2 pk; pk.x = p0; pk.y = p1;
            ((uint2*)C)[(size_t)n * (CG) + cg] = pk;
        }
    }
}

// ---------------- gather, D=128: one wave/node, bf16x2/lane, 8x unroll ----------------
template <bool RELU>
__global__ void k_gather128(const int* __restrict__ rowptr, const int* __restrict__ col,
                            const float* __restrict__ dinv, const uint32* __restrict__ t,
                            const float* __restrict__ b, float* __restrict__ outbuf) {
    unsigned wid = (blockIdx.x * blockDim.x + threadIdx.x) >> 6;
    int lane = threadIdx.x & 63;
    if (wid >= N_NODES) return;
    int beg = rowptr[wid], end = rowptr[wid + 1];
    uint32 p = t[(size_t)wid * 64 + lane];
    float ax = bf_lo(p), ay = bf_hi(p);
    int j = beg;
    for (; j + 8 <= end; j += 8) {
        int s0 = col[j], s1 = col[j+1], s2 = col[j+2], s3 = col[j+3];
        int s4 = col[j+4], s5 = col[j+5], s6 = col[j+6], s7 = col[j+7];
        uint32 v0 = t[(size_t)s0 * 64 + lane];
        uint32 v1 = t[(size_t)s1 * 64 + lane];
        uint32 v2 = t[(size_t)s2 * 64 + lane];
        uint32 v3 = t[(size_t)s3 * 64 + lane];
        uint32 v4 = t[(size_t)s4 * 64 + lane];
        uint32 v5 = t[(size_t)s5 * 64 + lane];
        uint32 v6 = t[(size_t)s6 * 64 + lane];
        uint32 v7 = t[(size_t)s7 * 64 + lane];
        ax += (bf_lo(v0) + bf_lo(v1)) + (bf_lo(v2) + bf_lo(v3))
            + ((bf_lo(v4) + bf_lo(v5)) + (bf_lo(v6) + bf_lo(v7)));
        ay += (bf_hi(v0) + bf_hi(v1)) + (bf_hi(v2) + bf_hi(v3))
            + ((bf_hi(v4) + bf_hi(v5)) + (bf_hi(v6) + bf_hi(v7)));
    }
    for (; j + 4 <= end; j += 4) {
        int s0 = col[j], s1 = col[j+1], s2 = col[j+2], s3 = col[j+3];
        uint32 v0 = t[(size_t)s0 * 64 + lane];
        uint32 v1 = t[(size_t)s1 * 64 + lane];
        uint32 v2 = t[(size_t)s2 * 64 + lane];
        uint32 v3 = t[(size_t)s3 * 64 + lane];
        ax += (bf_lo(v0) + bf_lo(v1)) + (bf_lo(v2) + bf_lo(v3));
        ay += (bf_hi(v0) + bf_hi(v1)) + (bf_hi(v2) + bf_hi(v3));
    }
    for (; j < end; ++j) {
        uint32 v = t[(size_t)col[j] * 64 + lane];
        ax += bf_lo(v); ay += bf_hi(v);
    }
    float di = dinv[wid];
    float2 bb = ((const float2*)b)[lane];
    float ox = di * ax + bb.x;
    float oy = di * ay + bb.y;
    if (RELU) { ox = fmaxf(ox, 0.f); oy = fmaxf(oy, 0.f); }
    ((float2*)outbuf)[(size_t)wid * 64 + lane] = make_float2(ox, oy);
}

// ---------------- gather, D=64 ----------------
template <bool RELU>
__global__ void k_gather64(const int* __restrict__ rowptr, const int* __restrict__ col,
                           const float* __restrict__ dinv, const ushort16* __restrict__ t,
                           const float* __restrict__ b, float* __restrict__ outbuf) {
    unsigned wid = (blockIdx.x * blockDim.x + threadIdx.x) >> 6;
    int lane = threadIdx.x & 63;
    if (wid >= N_NODES) return;
    int beg = rowptr[wid], end = rowptr[wid + 1];
    float acc = bf2f(t[(size_t)wid * 64 + lane]);
    int j = beg;
    for (; j + 8 <= end; j += 8) {
        int s0 = col[j], s1 = col[j+1], s2 = col[j+2], s3 = col[j+3];
        int s4 = col[j+4], s5 = col[j+5], s6 = col[j+6], s7 = col[j+7];
        float v0 = bf2f(t[(size_t)s0 * 64 + lane]);
        float v1 = bf2f(t[(size_t)s1 * 64 + lane]);
        float v2 = bf2f(t[(size_t)s2 * 64 + lane]);
        float v3 = bf2f(t[(size_t)s3 * 64 + lane]);
        float v4 = bf2f(t[(size_t)s4 * 64 + lane]);
        float v5 = bf2f(t[(size_t)s5 * 64 + lane]);
        float v6 = bf2f(t[(size_t)s6 * 64 + lane]);
        float v7 = bf2f(t[(size_t)s7 * 64 + lane]);
        acc += (v0 + v1) + (v2 + v3) + ((v4 + v5) + (v6 + v7));
    }
    for (; j + 4 <= end; j += 4) {
        int s0 = col[j], s1 = col[j+1], s2 = col[j+2], s3 = col[j+3];
        acc += (bf2f(t[(size_t)s0 * 64 + lane]) + bf2f(t[(size_t)s1 * 64 + lane]))
             + (bf2f(t[(size_t)s2 * 64 + lane]) + bf2f(t[(size_t)s3 * 64 + lane]));
    }
    for (; j < end; ++j) acc += bf2f(t[(size_t)col[j] * 64 + lane]);
    float o = dinv[wid] * acc + b[lane];
    if (RELU) o = fmaxf(o, 0.f);
    outbuf[(size_t)wid * 64 + lane] = o;
}

// ---------------- decode ----------------
__global__ void k_decode(const int* __restrict__ eli, const float* __restrict__ z,
                         float* __restrict__ out) {
    int e = blockIdx.x * blockDim.x + threadIdx.x;
    if (e >= N_EL) return;
    int a = eli[e];
    int b = eli[N_EL + e];
    const float4* za = (const float4*)(z + (size_t)a * 64);
    const float4* zb = (const float4*)(z + (size_t)b * 64);
    float acc = 0.0f;
#pragma unroll
    for (int i = 0; i < 16; ++i) {
        float4 x = za[i], y = zb[i];
        acc += x.x * y.x + x.y * y.y + x.z * y.z + x.w * y.w;
    }
    out[e] = acc;
}

extern "C" void kernel_launch(void* const* d_in, const int* in_sizes, int n_in,
                              void* d_out, int out_size, void* d_ws, size_t ws_size,
                              hipStream_t stream) {
    const float* x   = (const float*)d_in[0];
    const int*   ei  = (const int*)d_in[1];
    const int*   eli = (const int*)d_in[2];
    const float* W1  = (const float*)d_in[3];
    const float* b1  = (const float*)d_in[4];
    const float* W2  = (const float*)d_in[5];
    const float* b2  = (const float*)d_in[6];
    const float* W3  = (const float*)d_in[7];
    const float* b3  = (const float*)d_in[8];
    float* out = (float*)d_out;

    const int* srcA = ei;
    const int* dstA = ei + N_EDGES;

    // workspace layout (bytes) — non-overlapping (verified round 10):
    char* ws = (char*)d_ws;
    float*    dinv   = (float*)   (ws + 0);
    int*      cursor = (int*)     (ws + (512u << 10));
    int*      rowptr = (int*)     (ws + (1024u << 10));
    int*      bsum   = (int*)     (ws + (1888u << 10));
    int*      boff   = (int*)     (ws + (1896u << 10));
    int*      col    = (int*)     (ws + (2048u << 10));
    int*      r      = (int*)     (ws + (9u << 20));
    ushort16* t      = (ushort16*)(ws + (16u << 20));
    float*    agg    = (float*)   (ws + (48u << 20));

    const int B = 256;
    const int gE  = (N_EDGES + B - 1) / B;
    const int gG  = (N_NODES * 64 + B - 1) / B;
    const int gT  = (N_NODES + 63) / 64;
    const int gEL = (N_EL + B - 1) / B;

    // ---- CSR build (single atomic pass) ----
    hipMemsetAsync(cursor, 0, N_NODES * sizeof(int), stream);
    k_rank<<<gE, B, 0, stream>>>(dstA, cursor, r);
    k_scan1<<<NB_SCAN, 256, 0, stream>>>(cursor, rowptr, bsum, dinv);
    k_scan2<<<1, 512, 0, stream>>>(bsum, boff);
    k_scan3<<<NB_SCAN, 256, 0, stream>>>(rowptr, boff);
    k_fill2<<<gE, B, 0, stream>>>(srcA, dstA, rowptr, r, col);

    // ---- layer 1 ----
    k_gemm_lds<128><<<gT, B, 0, stream>>>(x, W1, dinv, t);
    k_gather128<true><<<gG, B, 0, stream>>>(rowptr, col, dinv, (const uint32*)t, b1, agg);
    // ---- layer 2 ----
    k_gemm_lds<128><<<gT, B, 0, stream>>>(agg, W2, dinv, t);
    k_gather128<true><<<gG, B, 0, stream>>>(rowptr, col, dinv, (const uint32*)t, b2, agg);
    // ---- layer 3 ----
    k_gemm_lds<64><<<gT, B, 0, stream>>>(agg, W3, dinv, t);
    k_gather64<false><<<gG, B, 0, stream>>>(rowptr, col, dinv, t, b3, agg);

    // ---- decode ----
    k_decode<<<gEL, B, 0, stream>>>(eli, agg, out);
}

// Round 13
// 531.444 us; speedup vs baseline: 1.3180x; 1.1714x over previous
//
#include <hip/hip_runtime.h>
#include <hip/hip_bf16.h>

#define N_NODES 100000
#define N_EDGES 1600000
#define N_EL    200000
// D_IN = D_HID = 128; layer-3 output D = 64. f32 inputs, int32 indices, f32 output.
// Round 13: GEMM moved to MFMA bf16 (16x16x32). W swizzled into LDS in B-frag
// order (32/16 KB); A-frags packed from global f32; C stored bf16 with dinv.
// VALU GEMM plateaued at 87us (VALU 41%, occ 29%); MFMA floor is memory ~25-35us.

#define NB_SCAN ((N_NODES + 255) / 256)   // 391

typedef unsigned int uint32;
typedef unsigned short ushort16;
typedef __attribute__((ext_vector_type(8))) short short8;   // 8 bf16 (4 VGPRs)
typedef __attribute__((ext_vector_type(4))) float f32x4;

static __device__ __forceinline__ ushort16 f2bf(float f) {
    uint32 u = __float_as_uint(f);
    u += 0x7fffu + ((u >> 16) & 1u);      // RNE
    return (ushort16)(u >> 16);
}
static __device__ __forceinline__ float bf_lo(uint32 p) { return __uint_as_float(p << 16); }
static __device__ __forceinline__ float bf_hi(uint32 p) { return __uint_as_float(p & 0xffff0000u); }
static __device__ __forceinline__ float bf2f(ushort16 h) { return __uint_as_float((uint32)h << 16); }

// ---------------- pass 1: rank + histogram in one atomic sweep ----------------
__global__ void k_rank(const int* __restrict__ dst, int* __restrict__ cursor,
                       int* __restrict__ r) {
    int e = blockIdx.x * blockDim.x + threadIdx.x;
    if (e < N_EDGES) r[e] = atomicAdd(&cursor[dst[e]], 1);
}

// ---------------- scan pass 1 (+ dinv); deg comes from cursor ----------------
__global__ void k_scan1(const int* __restrict__ deg, int* __restrict__ rowptr,
                        int* __restrict__ bsum, float* __restrict__ dinv) {
    __shared__ int s[256];
    int t = threadIdx.x;
    int i = blockIdx.x * 256 + t;
    int v = (i < N_NODES) ? deg[i] : 0;
    if (i < N_NODES) dinv[i] = 1.0f / sqrtf((float)(v + 1));   // +1 self-loop
    s[t] = v;
    __syncthreads();
    for (int off = 1; off < 256; off <<= 1) {
        int u = (t >= off) ? s[t - off] : 0;
        __syncthreads();
        s[t] += u;
        __syncthreads();
    }
    if (i < N_NODES) rowptr[i] = s[t] - v;          // exclusive, local
    if (t == 255) bsum[blockIdx.x] = s[255];
}

__global__ void k_scan2(const int* __restrict__ bsum, int* __restrict__ boff) {
    __shared__ int s[512];
    int t = threadIdx.x;
    int v = (t < NB_SCAN) ? bsum[t] : 0;
    s[t] = v;
    __syncthreads();
    for (int off = 1; off < 512; off <<= 1) {
        int u = (t >= off) ? s[t - off] : 0;
        __syncthreads();
        s[t] += u;
        __syncthreads();
    }
    if (t < NB_SCAN) boff[t] = s[t] - v;            // exclusive
    if (t == NB_SCAN - 1) boff[NB_SCAN] = s[t];     // total
}

__global__ void k_scan3(int* __restrict__ rowptr, const int* __restrict__ boff) {
    int i = blockIdx.x * 256 + threadIdx.x;
    if (i < N_NODES) rowptr[i] += boff[blockIdx.x];
    if (i == 0) rowptr[N_NODES] = boff[NB_SCAN];
}

// ---------------- pass 2: atomic-free CSR fill ----------------
__global__ void k_fill2(const int* __restrict__ src, const int* __restrict__ dst,
                        const int* __restrict__ rowptr, const int* __restrict__ r,
                        int* __restrict__ col) {
    int e = blockIdx.x * blockDim.x + threadIdx.x;
    if (e >= N_EDGES) return;
    int pos = rowptr[dst[e]] + r[e];
    __builtin_nontemporal_store(src[e], &col[pos]);
}

// ---------------- MFMA GEMM: t[n,:] = bf16( dinv[n] * (A[n,:128] @ W[128,D]) ) ----
// Block: 256 thr = 4 waves, 64 nodes (16/wave). mfma_f32_16x16x32_bf16.
// A-frag: lane holds A[m=lane&15][k=kt*32+quad*8+j] (2x float4 global + pack).
// B-frag: from LDS, pre-swizzled so lane reads 16B contiguous:
//   sB[((kt*NT+nt)*64 + lane)*8 + j] = bf16(W[kt*32+quad*8+j][nt*16+(lane&15)])
// C/D: col(n)=lane&15, row(m)=quad*4+reg  [m89-verified layout]
template <int D>
__global__ __launch_bounds__(256, 4) void k_gemm_mfma(const float* __restrict__ A,
        const float* __restrict__ W, const float* __restrict__ dinv,
        ushort16* __restrict__ C) {
    constexpr int NT = D / 16;                 // 8 (D=128) or 4 (D=64)
    __shared__ short sB[4 * NT * 64 * 8];      // 32 KB / 16 KB

    int tid = threadIdx.x;

    // stage W -> LDS in B-fragment order (coalesced global reads, scattered LDS writes)
    for (int idx = tid; idx < 128 * D; idx += 256) {
        int k = idx / D;
        int n = idx % D;
        int kt = k >> 5, kr = k & 31;
        int q = kr >> 3, j = kr & 7;
        int nt = n >> 4, nn = n & 15;
        sB[(((kt * NT + nt) * 64) + q * 16 + nn) * 8 + j] = (short)f2bf(W[idx]);
    }
    __syncthreads();

    int w = tid >> 6;
    int l = tid & 63;
    int q = l >> 4;
    int nn15 = l & 15;
    int m0 = blockIdx.x * 64 + w * 16;

    f32x4 acc[NT];
#pragma unroll
    for (int i = 0; i < NT; ++i) acc[i] = (f32x4){0.f, 0.f, 0.f, 0.f};

    int m = m0 + nn15;
    m = min(m, N_NODES - 1);                    // tail clamp (loads only)
    const float* arow = A + (size_t)m * 128;

#pragma unroll
    for (int kt = 0; kt < 4; ++kt) {
        const float* ap = arow + kt * 32 + q * 8;
        float4 a0 = *(const float4*)ap;
        float4 a1 = *(const float4*)(ap + 4);
        short8 af;
        af[0] = (short)f2bf(a0.x); af[1] = (short)f2bf(a0.y);
        af[2] = (short)f2bf(a0.z); af[3] = (short)f2bf(a0.w);
        af[4] = (short)f2bf(a1.x); af[5] = (short)f2bf(a1.y);
        af[6] = (short)f2bf(a1.z); af[7] = (short)f2bf(a1.w);
#pragma unroll
        for (int nt = 0; nt < NT; ++nt) {
            short8 bf = *(const short8*)&sB[((kt * NT + nt) * 64 + l) * 8];
            acc[nt] = __builtin_amdgcn_mfma_f32_16x16x32_bf16(af, bf, acc[nt], 0, 0, 0);
        }
    }

    // epilogue: node = m0 + q*4 + r, col = nt*16 + nn15
    float4 dv = *(const float4*)(dinv + m0 + 4 * q);   // dinv[m0+q*4 .. +3]
    const float* dvp = (const float*)&dv;
    ushort16* Cs = (ushort16*)C;
#pragma unroll
    for (int nt = 0; nt < NT; ++nt) {
#pragma unroll
        for (int r = 0; r < 4; ++r) {
            int node = m0 + q * 4 + r;
            if (node < N_NODES) {
                float val = acc[nt][r] * dvp[r];
                Cs[(size_t)node * D + nt * 16 + nn15] = f2bf(val);
            }
        }
    }
}

// ---------------- gather, D=128: one wave/node, bf16x2/lane, 8x unroll ----------------
template <bool RELU>
__global__ void k_gather128(const int* __restrict__ rowptr, const int* __restrict__ col,
                            const float* __restrict__ dinv, const uint32* __restrict__ t,
                            const float* __restrict__ b, float* __restrict__ outbuf) {
    unsigned wid = (blockIdx.x * blockDim.x + threadIdx.x) >> 6;
    int lane = threadIdx.x & 63;
    if (wid >= N_NODES) return;
    int beg = rowptr[wid], end = rowptr[wid + 1];
    uint32 p = t[(size_t)wid * 64 + lane];
    float ax = bf_lo(p), ay = bf_hi(p);
    int j = beg;
    for (; j + 8 <= end; j += 8) {
        int s0 = col[j], s1 = col[j+1], s2 = col[j+2], s3 = col[j+3];
        int s4 = col[j+4], s5 = col[j+5], s6 = col[j+6], s7 = col[j+7];
        uint32 v0 = t[(size_t)s0 * 64 + lane];
        uint32 v1 = t[(size_t)s1 * 64 + lane];
        uint32 v2 = t[(size_t)s2 * 64 + lane];
        uint32 v3 = t[(size_t)s3 * 64 + lane];
        uint32 v4 = t[(size_t)s4 * 64 + lane];
        uint32 v5 = t[(size_t)s5 * 64 + lane];
        uint32 v6 = t[(size_t)s6 * 64 + lane];
        uint32 v7 = t[(size_t)s7 * 64 + lane];
        ax += (bf_lo(v0) + bf_lo(v1)) + (bf_lo(v2) + bf_lo(v3))
            + ((bf_lo(v4) + bf_lo(v5)) + (bf_lo(v6) + bf_lo(v7)));
        ay += (bf_hi(v0) + bf_hi(v1)) + (bf_hi(v2) + bf_hi(v3))
            + ((bf_hi(v4) + bf_hi(v5)) + (bf_hi(v6) + bf_hi(v7)));
    }
    for (; j + 4 <= end; j += 4) {
        int s0 = col[j], s1 = col[j+1], s2 = col[j+2], s3 = col[j+3];
        uint32 v0 = t[(size_t)s0 * 64 + lane];
        uint32 v1 = t[(size_t)s1 * 64 + lane];
        uint32 v2 = t[(size_t)s2 * 64 + lane];
        uint32 v3 = t[(size_t)s3 * 64 + lane];
        ax += (bf_lo(v0) + bf_lo(v1)) + (bf_lo(v2) + bf_lo(v3));
        ay += (bf_hi(v0) + bf_hi(v1)) + (bf_hi(v2) + bf_hi(v3));
    }
    for (; j < end; ++j) {
        uint32 v = t[(size_t)col[j] * 64 + lane];
        ax += bf_lo(v); ay += bf_hi(v);
    }
    float di = dinv[wid];
    float2 bb = ((const float2*)b)[lane];
    float ox = di * ax + bb.x;
    float oy = di * ay + bb.y;
    if (RELU) { ox = fmaxf(ox, 0.f); oy = fmaxf(oy, 0.f); }
    ((float2*)outbuf)[(size_t)wid * 64 + lane] = make_float2(ox, oy);
}

// ---------------- gather, D=64 ----------------
template <bool RELU>
__global__ void k_gather64(const int* __restrict__ rowptr, const int* __restrict__ col,
                           const float* __restrict__ dinv, const ushort16* __restrict__ t,
                           const float* __restrict__ b, float* __restrict__ outbuf) {
    unsigned wid = (blockIdx.x * blockDim.x + threadIdx.x) >> 6;
    int lane = threadIdx.x & 63;
    if (wid >= N_NODES) return;
    int beg = rowptr[wid], end = rowptr[wid + 1];
    float acc = bf2f(t[(size_t)wid * 64 + lane]);
    int j = beg;
    for (; j + 8 <= end; j += 8) {
        int s0 = col[j], s1 = col[j+1], s2 = col[j+2], s3 = col[j+3];
        int s4 = col[j+4], s5 = col[j+5], s6 = col[j+6], s7 = col[j+7];
        float v0 = bf2f(t[(size_t)s0 * 64 + lane]);
        float v1 = bf2f(t[(size_t)s1 * 64 + lane]);
        float v2 = bf2f(t[(size_t)s2 * 64 + lane]);
        float v3 = bf2f(t[(size_t)s3 * 64 + lane]);
        float v4 = bf2f(t[(size_t)s4 * 64 + lane]);
        float v5 = bf2f(t[(size_t)s5 * 64 + lane]);
        float v6 = bf2f(t[(size_t)s6 * 64 + lane]);
        float v7 = bf2f(t[(size_t)s7 * 64 + lane]);
        acc += (v0 + v1) + (v2 + v3) + ((v4 + v5) + (v6 + v7));
    }
    for (; j + 4 <= end; j += 4) {
        int s0 = col[j], s1 = col[j+1], s2 = col[j+2], s3 = col[j+3];
        acc += (bf2f(t[(size_t)s0 * 64 + lane]) + bf2f(t[(size_t)s1 * 64 + lane]))
             + (bf2f(t[(size_t)s2 * 64 + lane]) + bf2f(t[(size_t)s3 * 64 + lane]));
    }
    for (; j < end; ++j) acc += bf2f(t[(size_t)col[j] * 64 + lane]);
    float o = dinv[wid] * acc + b[lane];
    if (RELU) o = fmaxf(o, 0.f);
    outbuf[(size_t)wid * 64 + lane] = o;
}

// ---------------- decode ----------------
__global__ void k_decode(const int* __restrict__ eli, const float* __restrict__ z,
                         float* __restrict__ out) {
    int e = blockIdx.x * blockDim.x + threadIdx.x;
    if (e >= N_EL) return;
    int a = eli[e];
    int b = eli[N_EL + e];
    const float4* za = (const float4*)(z + (size_t)a * 64);
    const float4* zb = (const float4*)(z + (size_t)b * 64);
    float acc = 0.0f;
#pragma unroll
    for (int i = 0; i < 16; ++i) {
        float4 x = za[i], y = zb[i];
        acc += x.x * y.x + x.y * y.y + x.z * y.z + x.w * y.w;
    }
    out[e] = acc;
}

extern "C" void kernel_launch(void* const* d_in, const int* in_sizes, int n_in,
                              void* d_out, int out_size, void* d_ws, size_t ws_size,
                              hipStream_t stream) {
    const float* x   = (const float*)d_in[0];
    const int*   ei  = (const int*)d_in[1];
    const int*   eli = (const int*)d_in[2];
    const float* W1  = (const float*)d_in[3];
    const float* b1  = (const float*)d_in[4];
    const float* W2  = (const float*)d_in[5];
    const float* b2  = (const float*)d_in[6];
    const float* W3  = (const float*)d_in[7];
    const float* b3  = (const float*)d_in[8];
    float* out = (float*)d_out;

    const int* srcA = ei;
    const int* dstA = ei + N_EDGES;

    // workspace layout (bytes) — non-overlapping (verified round 10):
    char* ws = (char*)d_ws;
    float*    dinv   = (float*)   (ws + 0);
    int*      cursor = (int*)     (ws + (512u << 10));
    int*      rowptr = (int*)     (ws + (1024u << 10));
    int*      bsum   = (int*)     (ws + (1888u << 10));
    int*      boff   = (int*)     (ws + (1896u << 10));
    int*      col    = (int*)     (ws + (2048u << 10));
    int*      r      = (int*)     (ws + (9u << 20));
    ushort16* t      = (ushort16*)(ws + (16u << 20));
    float*    agg    = (float*)   (ws + (48u << 20));

    const int B = 256;
    const int gE  = (N_EDGES + B - 1) / B;
    const int gG  = (N_NODES * 64 + B - 1) / B;
    const int gT  = (N_NODES + 63) / 64;      // 1563
    const int gEL = (N_EL + B - 1) / B;

    // ---- CSR build (single atomic pass) ----
    hipMemsetAsync(cursor, 0, N_NODES * sizeof(int), stream);
    k_rank<<<gE, B, 0, stream>>>(dstA, cursor, r);
    k_scan1<<<NB_SCAN, 256, 0, stream>>>(cursor, rowptr, bsum, dinv);
    k_scan2<<<1, 512, 0, stream>>>(bsum, boff);
    k_scan3<<<NB_SCAN, 256, 0, stream>>>(rowptr, boff);
    k_fill2<<<gE, B, 0, stream>>>(srcA, dstA, rowptr, r, col);

    // ---- layer 1 ----
    k_gemm_mfma<128><<<gT, B, 0, stream>>>(x, W1, dinv, t);
    k_gather128<true><<<gG, B, 0, stream>>>(rowptr, col, dinv, (const uint32*)t, b1, agg);
    // ---- layer 2 ----
    k_gemm_mfma<128><<<gT, B, 0, stream>>>(agg, W2, dinv, t);
    k_gather128<true><<<gG, B, 0, stream>>>(rowptr, col, dinv, (const uint32*)t, b2, agg);
    // ---- layer 3 ----
    k_gemm_mfma<64><<<gT, B, 0, stream>>>(agg, W3, dinv, t);
    k_gather64<false><<<gG, B, 0, stream>>>(rowptr, col, dinv, t, b3, agg);

    // ---- decode ----
    k_decode<<<gEL, B, 0, stream>>>(eli, agg, out);
}

// Round 14
// 491.036 us; speedup vs baseline: 1.4265x; 1.0823x over previous
//
#include <hip/hip_runtime.h>
#include <hip/hip_bf16.h>

#define N_NODES 100000
#define N_EDGES 1600000
#define N_EL    200000
// D_IN = D_HID = 128; layer-3 output D = 64. f32 inputs, int32 indices, f32 output.
// Round 14: all inter-layer state bf16. agg stored bf16 (gathers pack on store;
// GEMM layers 2-3 load A as short8 directly -> zero extra rounding vs round 13,
// since MFMA already rounded A to bf16). Halves gather write stream + GEMM A reads
// + decode reads; less L3 eviction of the gather-hot t table.

#define NB_SCAN ((N_NODES + 255) / 256)   // 391

typedef unsigned int uint32;
typedef unsigned short ushort16;
typedef __attribute__((ext_vector_type(8))) short short8;   // 8 bf16 (4 VGPRs)
typedef __attribute__((ext_vector_type(4))) float f32x4;

static __device__ __forceinline__ ushort16 f2bf(float f) {
    uint32 u = __float_as_uint(f);
    u += 0x7fffu + ((u >> 16) & 1u);      // RNE
    return (ushort16)(u >> 16);
}
static __device__ __forceinline__ float bf_lo(uint32 p) { return __uint_as_float(p << 16); }
static __device__ __forceinline__ float bf_hi(uint32 p) { return __uint_as_float(p & 0xffff0000u); }
static __device__ __forceinline__ float bf2f(ushort16 h) { return __uint_as_float((uint32)h << 16); }

// ---------------- pass 1: rank + histogram in one atomic sweep ----------------
__global__ void k_rank(const int* __restrict__ dst, int* __restrict__ cursor,
                       int* __restrict__ r) {
    int e = blockIdx.x * blockDim.x + threadIdx.x;
    if (e < N_EDGES) r[e] = atomicAdd(&cursor[dst[e]], 1);
}

// ---------------- scan pass 1 (+ dinv); deg comes from cursor ----------------
__global__ void k_scan1(const int* __restrict__ deg, int* __restrict__ rowptr,
                        int* __restrict__ bsum, float* __restrict__ dinv) {
    __shared__ int s[256];
    int t = threadIdx.x;
    int i = blockIdx.x * 256 + t;
    int v = (i < N_NODES) ? deg[i] : 0;
    if (i < N_NODES) dinv[i] = 1.0f / sqrtf((float)(v + 1));   // +1 self-loop
    s[t] = v;
    __syncthreads();
    for (int off = 1; off < 256; off <<= 1) {
        int u = (t >= off) ? s[t - off] : 0;
        __syncthreads();
        s[t] += u;
        __syncthreads();
    }
    if (i < N_NODES) rowptr[i] = s[t] - v;          // exclusive, local
    if (t == 255) bsum[blockIdx.x] = s[255];
}

__global__ void k_scan2(const int* __restrict__ bsum, int* __restrict__ boff) {
    __shared__ int s[512];
    int t = threadIdx.x;
    int v = (t < NB_SCAN) ? bsum[t] : 0;
    s[t] = v;
    __syncthreads();
    for (int off = 1; off < 512; off <<= 1) {
        int u = (t >= off) ? s[t - off] : 0;
        __syncthreads();
        s[t] += u;
        __syncthreads();
    }
    if (t < NB_SCAN) boff[t] = s[t] - v;            // exclusive
    if (t == NB_SCAN - 1) boff[NB_SCAN] = s[t];     // total
}

__global__ void k_scan3(int* __restrict__ rowptr, const int* __restrict__ boff) {
    int i = blockIdx.x * 256 + threadIdx.x;
    if (i < N_NODES) rowptr[i] += boff[blockIdx.x];
    if (i == 0) rowptr[N_NODES] = boff[NB_SCAN];
}

// ---------------- pass 2: atomic-free CSR fill ----------------
__global__ void k_fill2(const int* __restrict__ src, const int* __restrict__ dst,
                        const int* __restrict__ rowptr, const int* __restrict__ r,
                        int* __restrict__ col) {
    int e = blockIdx.x * blockDim.x + threadIdx.x;
    if (e >= N_EDGES) return;
    int pos = rowptr[dst[e]] + r[e];
    __builtin_nontemporal_store(src[e], &col[pos]);
}

// ---------------- A-fragment loaders ----------------
static __device__ __forceinline__ short8 load_afrag(const float* arow, int off) {
    float4 a0 = *(const float4*)(arow + off);
    float4 a1 = *(const float4*)(arow + off + 4);
    short8 af;
    af[0] = (short)f2bf(a0.x); af[1] = (short)f2bf(a0.y);
    af[2] = (short)f2bf(a0.z); af[3] = (short)f2bf(a0.w);
    af[4] = (short)f2bf(a1.x); af[5] = (short)f2bf(a1.y);
    af[6] = (short)f2bf(a1.z); af[7] = (short)f2bf(a1.w);
    return af;
}
static __device__ __forceinline__ short8 load_afrag(const ushort16* arow, int off) {
    return *(const short8*)(arow + off);   // 16B aligned (row=256B, off multiple of 8)
}

// ---------------- MFMA GEMM: t[n,:] = bf16( dinv[n] * (A[n,:128] @ W[128,D]) ) ----
// Block: 256 thr = 4 waves, 64 nodes (16/wave). mfma_f32_16x16x32_bf16.
// C/D: col(n)=lane&15, row(m)=quad*4+reg  [m89-verified layout]
template <int D, typename AT>
__global__ __launch_bounds__(256, 4) void k_gemm_mfma(const AT* __restrict__ A,
        const float* __restrict__ W, const float* __restrict__ dinv,
        ushort16* __restrict__ C) {
    constexpr int NT = D / 16;                 // 8 (D=128) or 4 (D=64)
    __shared__ short sB[4 * NT * 64 * 8];      // 32 KB / 16 KB

    int tid = threadIdx.x;

    // stage W -> LDS in B-fragment order
    for (int idx = tid; idx < 128 * D; idx += 256) {
        int k = idx / D;
        int n = idx % D;
        int kt = k >> 5, kr = k & 31;
        int q = kr >> 3, j = kr & 7;
        int nt = n >> 4, nn = n & 15;
        sB[(((kt * NT + nt) * 64) + q * 16 + nn) * 8 + j] = (short)f2bf(W[idx]);
    }
    __syncthreads();

    int w = tid >> 6;
    int l = tid & 63;
    int q = l >> 4;
    int nn15 = l & 15;
    int m0 = blockIdx.x * 64 + w * 16;

    f32x4 acc[NT];
#pragma unroll
    for (int i = 0; i < NT; ++i) acc[i] = (f32x4){0.f, 0.f, 0.f, 0.f};

    int m = m0 + nn15;
    m = min(m, N_NODES - 1);                    // tail clamp (loads only)
    const AT* arow = A + (size_t)m * 128;

#pragma unroll
    for (int kt = 0; kt < 4; ++kt) {
        short8 af = load_afrag(arow, kt * 32 + q * 8);
#pragma unroll
        for (int nt = 0; nt < NT; ++nt) {
            short8 bf = *(const short8*)&sB[((kt * NT + nt) * 64 + l) * 8];
            acc[nt] = __builtin_amdgcn_mfma_f32_16x16x32_bf16(af, bf, acc[nt], 0, 0, 0);
        }
    }

    // epilogue: node = m0 + q*4 + r, col = nt*16 + nn15
    float4 dv = *(const float4*)(dinv + m0 + 4 * q);
    const float* dvp = (const float*)&dv;
#pragma unroll
    for (int nt = 0; nt < NT; ++nt) {
#pragma unroll
        for (int r = 0; r < 4; ++r) {
            int node = m0 + q * 4 + r;
            if (node < N_NODES) {
                float val = acc[nt][r] * dvp[r];
                C[(size_t)node * D + nt * 16 + nn15] = f2bf(val);
            }
        }
    }
}

// ---------------- gather, D=128: one wave/node, bf16x2/lane, 8x unroll; bf16 out ----
template <bool RELU>
__global__ void k_gather128(const int* __restrict__ rowptr, const int* __restrict__ col,
                            const float* __restrict__ dinv, const uint32* __restrict__ t,
                            const float* __restrict__ b, uint32* __restrict__ outbuf) {
    unsigned wid = (blockIdx.x * blockDim.x + threadIdx.x) >> 6;
    int lane = threadIdx.x & 63;
    if (wid >= N_NODES) return;
    int beg = rowptr[wid], end = rowptr[wid + 1];
    uint32 p = t[(size_t)wid * 64 + lane];
    float ax = bf_lo(p), ay = bf_hi(p);
    int j = beg;
    for (; j + 8 <= end; j += 8) {
        int s0 = col[j], s1 = col[j+1], s2 = col[j+2], s3 = col[j+3];
        int s4 = col[j+4], s5 = col[j+5], s6 = col[j+6], s7 = col[j+7];
        uint32 v0 = t[(size_t)s0 * 64 + lane];
        uint32 v1 = t[(size_t)s1 * 64 + lane];
        uint32 v2 = t[(size_t)s2 * 64 + lane];
        uint32 v3 = t[(size_t)s3 * 64 + lane];
        uint32 v4 = t[(size_t)s4 * 64 + lane];
        uint32 v5 = t[(size_t)s5 * 64 + lane];
        uint32 v6 = t[(size_t)s6 * 64 + lane];
        uint32 v7 = t[(size_t)s7 * 64 + lane];
        ax += (bf_lo(v0) + bf_lo(v1)) + (bf_lo(v2) + bf_lo(v3))
            + ((bf_lo(v4) + bf_lo(v5)) + (bf_lo(v6) + bf_lo(v7)));
        ay += (bf_hi(v0) + bf_hi(v1)) + (bf_hi(v2) + bf_hi(v3))
            + ((bf_hi(v4) + bf_hi(v5)) + (bf_hi(v6) + bf_hi(v7)));
    }
    for (; j + 4 <= end; j += 4) {
        int s0 = col[j], s1 = col[j+1], s2 = col[j+2], s3 = col[j+3];
        uint32 v0 = t[(size_t)s0 * 64 + lane];
        uint32 v1 = t[(size_t)s1 * 64 + lane];
        uint32 v2 = t[(size_t)s2 * 64 + lane];
        uint32 v3 = t[(size_t)s3 * 64 + lane];
        ax += (bf_lo(v0) + bf_lo(v1)) + (bf_lo(v2) + bf_lo(v3));
        ay += (bf_hi(v0) + bf_hi(v1)) + (bf_hi(v2) + bf_hi(v3));
    }
    for (; j < end; ++j) {
        uint32 v = t[(size_t)col[j] * 64 + lane];
        ax += bf_lo(v); ay += bf_hi(v);
    }
    float di = dinv[wid];
    float2 bb = ((const float2*)b)[lane];
    float ox = di * ax + bb.x;
    float oy = di * ay + bb.y;
    if (RELU) { ox = fmaxf(ox, 0.f); oy = fmaxf(oy, 0.f); }
    outbuf[(size_t)wid * 64 + lane] = (uint32)f2bf(ox) | ((uint32)f2bf(oy) << 16);
}

// ---------------- gather, D=64: bf16 out ----------------
template <bool RELU>
__global__ void k_gather64(const int* __restrict__ rowptr, const int* __restrict__ col,
                           const float* __restrict__ dinv, const ushort16* __restrict__ t,
                           const float* __restrict__ b, ushort16* __restrict__ outbuf) {
    unsigned wid = (blockIdx.x * blockDim.x + threadIdx.x) >> 6;
    int lane = threadIdx.x & 63;
    if (wid >= N_NODES) return;
    int beg = rowptr[wid], end = rowptr[wid + 1];
    float acc = bf2f(t[(size_t)wid * 64 + lane]);
    int j = beg;
    for (; j + 8 <= end; j += 8) {
        int s0 = col[j], s1 = col[j+1], s2 = col[j+2], s3 = col[j+3];
        int s4 = col[j+4], s5 = col[j+5], s6 = col[j+6], s7 = col[j+7];
        float v0 = bf2f(t[(size_t)s0 * 64 + lane]);
        float v1 = bf2f(t[(size_t)s1 * 64 + lane]);
        float v2 = bf2f(t[(size_t)s2 * 64 + lane]);
        float v3 = bf2f(t[(size_t)s3 * 64 + lane]);
        float v4 = bf2f(t[(size_t)s4 * 64 + lane]);
        float v5 = bf2f(t[(size_t)s5 * 64 + lane]);
        float v6 = bf2f(t[(size_t)s6 * 64 + lane]);
        float v7 = bf2f(t[(size_t)s7 * 64 + lane]);
        acc += (v0 + v1) + (v2 + v3) + ((v4 + v5) + (v6 + v7));
    }
    for (; j + 4 <= end; j += 4) {
        int s0 = col[j], s1 = col[j+1], s2 = col[j+2], s3 = col[j+3];
        acc += (bf2f(t[(size_t)s0 * 64 + lane]) + bf2f(t[(size_t)s1 * 64 + lane]))
             + (bf2f(t[(size_t)s2 * 64 + lane]) + bf2f(t[(size_t)s3 * 64 + lane]));
    }
    for (; j < end; ++j) acc += bf2f(t[(size_t)col[j] * 64 + lane]);
    float o = dinv[wid] * acc + b[lane];
    if (RELU) o = fmaxf(o, 0.f);
    outbuf[(size_t)wid * 64 + lane] = f2bf(o);
}

// ---------------- decode: z is bf16 [N x 64] ----------------
__global__ void k_decode(const int* __restrict__ eli, const ushort16* __restrict__ z,
                         float* __restrict__ out) {
    int e = blockIdx.x * blockDim.x + threadIdx.x;
    if (e >= N_EL) return;
    int a = eli[e];
    int b = eli[N_EL + e];
    const uint4* za = (const uint4*)(z + (size_t)a * 64);
    const uint4* zb = (const uint4*)(z + (size_t)b * 64);
    float acc = 0.0f;
#pragma unroll
    for (int i = 0; i < 8; ++i) {      // 8 x 16B = 128B = 64 bf16
        uint4 va = za[i], vb = zb[i];
        acc += bf_lo(va.x) * bf_lo(vb.x) + bf_hi(va.x) * bf_hi(vb.x);
        acc += bf_lo(va.y) * bf_lo(vb.y) + bf_hi(va.y) * bf_hi(vb.y);
        acc += bf_lo(va.z) * bf_lo(vb.z) + bf_hi(va.z) * bf_hi(vb.z);
        acc += bf_lo(va.w) * bf_lo(vb.w) + bf_hi(va.w) * bf_hi(vb.w);
    }
    out[e] = acc;
}

extern "C" void kernel_launch(void* const* d_in, const int* in_sizes, int n_in,
                              void* d_out, int out_size, void* d_ws, size_t ws_size,
                              hipStream_t stream) {
    const float* x   = (const float*)d_in[0];
    const int*   ei  = (const int*)d_in[1];
    const int*   eli = (const int*)d_in[2];
    const float* W1  = (const float*)d_in[3];
    const float* b1  = (const float*)d_in[4];
    const float* W2  = (const float*)d_in[5];
    const float* b2  = (const float*)d_in[6];
    const float* W3  = (const float*)d_in[7];
    const float* b3  = (const float*)d_in[8];
    float* out = (float*)d_out;

    const int* srcA = ei;
    const int* dstA = ei + N_EDGES;

    // workspace layout (bytes) — non-overlapping:
    //   dinv   [0, 400,000)   cursor [512K, +400K)   rowptr [1M, +400K+4)
    //   bsum [1888K) boff [1896K)   col [2M, 8.4M)   r [9M, 15.4M)
    //   t    [16M, +25.6M)  bf16 N x 128
    //   aggb [48M, +25.6M)  bf16 N x 128 (layers), N x 64 (final z)
    char* ws = (char*)d_ws;
    float*    dinv   = (float*)   (ws + 0);
    int*      cursor = (int*)     (ws + (512u << 10));
    int*      rowptr = (int*)     (ws + (1024u << 10));
    int*      bsum   = (int*)     (ws + (1888u << 10));
    int*      boff   = (int*)     (ws + (1896u << 10));
    int*      col    = (int*)     (ws + (2048u << 10));
    int*      r      = (int*)     (ws + (9u << 20));
    ushort16* t      = (ushort16*)(ws + (16u << 20));
    ushort16* aggb   = (ushort16*)(ws + (48u << 20));

    const int B = 256;
    const int gE  = (N_EDGES + B - 1) / B;
    const int gG  = (N_NODES * 64 + B - 1) / B;
    const int gT  = (N_NODES + 63) / 64;      // 1563
    const int gEL = (N_EL + B - 1) / B;

    // ---- CSR build (single atomic pass) ----
    hipMemsetAsync(cursor, 0, N_NODES * sizeof(int), stream);
    k_rank<<<gE, B, 0, stream>>>(dstA, cursor, r);
    k_scan1<<<NB_SCAN, 256, 0, stream>>>(cursor, rowptr, bsum, dinv);
    k_scan2<<<1, 512, 0, stream>>>(bsum, boff);
    k_scan3<<<NB_SCAN, 256, 0, stream>>>(rowptr, boff);
    k_fill2<<<gE, B, 0, stream>>>(srcA, dstA, rowptr, r, col);

    // ---- layer 1 (A = x, f32) ----
    k_gemm_mfma<128, float><<<gT, B, 0, stream>>>(x, W1, dinv, t);
    k_gather128<true><<<gG, B, 0, stream>>>(rowptr, col, dinv, (const uint32*)t, b1,
                                            (uint32*)aggb);
    // ---- layer 2 (A = h1, bf16) ----
    k_gemm_mfma<128, ushort16><<<gT, B, 0, stream>>>(aggb, W2, dinv, t);
    k_gather128<true><<<gG, B, 0, stream>>>(rowptr, col, dinv, (const uint32*)t, b2,
                                            (uint32*)aggb);
    // ---- layer 3 (A = h2, bf16) ----
    k_gemm_mfma<64, ushort16><<<gT, B, 0, stream>>>(aggb, W3, dinv, t);
    k_gather64<false><<<gG, B, 0, stream>>>(rowptr, col, dinv, t, b3, aggb);

    // ---- decode ----
    k_decode<<<gEL, B, 0, stream>>>(eli, aggb, out);
}

// Round 15
// 487.554 us; speedup vs baseline: 1.4366x; 1.0071x over previous
//
#include <hip/hip_runtime.h>
#include <hip/hip_bf16.h>

#define N_NODES 100000
#define N_EDGES 1600000
#define N_EL    200000
// D_IN = D_HID = 128; layer-3 output D = 64. f32 inputs, int32 indices, f32 output.
// Round 15: pad rank's atomic counters to 1 per 64B line (cursor[dst*16]).
// Round-14 rank counters (VALU 0.5%, HBM 11%, occ 67%, 68us) indicate TCC
// line-level RMW serialization: 16 packed counters/line x 16 hits = 256 RMW/line.

#define NB_SCAN ((N_NODES + 255) / 256)   // 391
#define CPAD 16                            // ints per counter line

typedef unsigned int uint32;
typedef unsigned short ushort16;
typedef __attribute__((ext_vector_type(8))) short short8;   // 8 bf16 (4 VGPRs)
typedef __attribute__((ext_vector_type(4))) float f32x4;

static __device__ __forceinline__ ushort16 f2bf(float f) {
    uint32 u = __float_as_uint(f);
    u += 0x7fffu + ((u >> 16) & 1u);      // RNE
    return (ushort16)(u >> 16);
}
static __device__ __forceinline__ float bf_lo(uint32 p) { return __uint_as_float(p << 16); }
static __device__ __forceinline__ float bf_hi(uint32 p) { return __uint_as_float(p & 0xffff0000u); }
static __device__ __forceinline__ float bf2f(ushort16 h) { return __uint_as_float((uint32)h << 16); }

// ---------------- pass 1: rank + histogram, line-padded counters ----------------
__global__ void k_rank(const int* __restrict__ dst, int* __restrict__ cpad,
                       int* __restrict__ r) {
    int e = blockIdx.x * blockDim.x + threadIdx.x;
    if (e < N_EDGES) r[e] = atomicAdd(&cpad[(size_t)dst[e] * CPAD], 1);
}

// ---------------- scan pass 1 (+ dinv); deg read from padded counters ----------------
__global__ void k_scan1(const int* __restrict__ cpad, int* __restrict__ rowptr,
                        int* __restrict__ bsum, float* __restrict__ dinv) {
    __shared__ int s[256];
    int t = threadIdx.x;
    int i = blockIdx.x * 256 + t;
    int v = (i < N_NODES) ? cpad[(size_t)i * CPAD] : 0;
    if (i < N_NODES) dinv[i] = 1.0f / sqrtf((float)(v + 1));   // +1 self-loop
    s[t] = v;
    __syncthreads();
    for (int off = 1; off < 256; off <<= 1) {
        int u = (t >= off) ? s[t - off] : 0;
        __syncthreads();
        s[t] += u;
        __syncthreads();
    }
    if (i < N_NODES) rowptr[i] = s[t] - v;          // exclusive, local
    if (t == 255) bsum[blockIdx.x] = s[255];
}

__global__ void k_scan2(const int* __restrict__ bsum, int* __restrict__ boff) {
    __shared__ int s[512];
    int t = threadIdx.x;
    int v = (t < NB_SCAN) ? bsum[t] : 0;
    s[t] = v;
    __syncthreads();
    for (int off = 1; off < 512; off <<= 1) {
        int u = (t >= off) ? s[t - off] : 0;
        __syncthreads();
        s[t] += u;
        __syncthreads();
    }
    if (t < NB_SCAN) boff[t] = s[t] - v;            // exclusive
    if (t == NB_SCAN - 1) boff[NB_SCAN] = s[t];     // total
}

__global__ void k_scan3(int* __restrict__ rowptr, const int* __restrict__ boff) {
    int i = blockIdx.x * 256 + threadIdx.x;
    if (i < N_NODES) rowptr[i] += boff[blockIdx.x];
    if (i == 0) rowptr[N_NODES] = boff[NB_SCAN];
}

// ---------------- pass 2: atomic-free CSR fill ----------------
__global__ void k_fill2(const int* __restrict__ src, const int* __restrict__ dst,
                        const int* __restrict__ rowptr, const int* __restrict__ r,
                        int* __restrict__ col) {
    int e = blockIdx.x * blockDim.x + threadIdx.x;
    if (e >= N_EDGES) return;
    int pos = rowptr[dst[e]] + r[e];
    __builtin_nontemporal_store(src[e], &col[pos]);
}

// ---------------- A-fragment loaders ----------------
static __device__ __forceinline__ short8 load_afrag(const float* arow, int off) {
    float4 a0 = *(const float4*)(arow + off);
    float4 a1 = *(const float4*)(arow + off + 4);
    short8 af;
    af[0] = (short)f2bf(a0.x); af[1] = (short)f2bf(a0.y);
    af[2] = (short)f2bf(a0.z); af[3] = (short)f2bf(a0.w);
    af[4] = (short)f2bf(a1.x); af[5] = (short)f2bf(a1.y);
    af[6] = (short)f2bf(a1.z); af[7] = (short)f2bf(a1.w);
    return af;
}
static __device__ __forceinline__ short8 load_afrag(const ushort16* arow, int off) {
    return *(const short8*)(arow + off);   // 16B aligned
}

// ---------------- MFMA GEMM: t[n,:] = bf16( dinv[n] * (A[n,:128] @ W[128,D]) ) ----
template <int D, typename AT>
__global__ __launch_bounds__(256, 4) void k_gemm_mfma(const AT* __restrict__ A,
        const float* __restrict__ W, const float* __restrict__ dinv,
        ushort16* __restrict__ C) {
    constexpr int NT = D / 16;                 // 8 (D=128) or 4 (D=64)
    __shared__ short sB[4 * NT * 64 * 8];      // 32 KB / 16 KB

    int tid = threadIdx.x;

    // stage W -> LDS in B-fragment order
    for (int idx = tid; idx < 128 * D; idx += 256) {
        int k = idx / D;
        int n = idx % D;
        int kt = k >> 5, kr = k & 31;
        int q = kr >> 3, j = kr & 7;
        int nt = n >> 4, nn = n & 15;
        sB[(((kt * NT + nt) * 64) + q * 16 + nn) * 8 + j] = (short)f2bf(W[idx]);
    }
    __syncthreads();

    int w = tid >> 6;
    int l = tid & 63;
    int q = l >> 4;
    int nn15 = l & 15;
    int m0 = blockIdx.x * 64 + w * 16;

    f32x4 acc[NT];
#pragma unroll
    for (int i = 0; i < NT; ++i) acc[i] = (f32x4){0.f, 0.f, 0.f, 0.f};

    int m = m0 + nn15;
    m = min(m, N_NODES - 1);                    // tail clamp (loads only)
    const AT* arow = A + (size_t)m * 128;

#pragma unroll
    for (int kt = 0; kt < 4; ++kt) {
        short8 af = load_afrag(arow, kt * 32 + q * 8);
#pragma unroll
        for (int nt = 0; nt < NT; ++nt) {
            short8 bf = *(const short8*)&sB[((kt * NT + nt) * 64 + l) * 8];
            acc[nt] = __builtin_amdgcn_mfma_f32_16x16x32_bf16(af, bf, acc[nt], 0, 0, 0);
        }
    }

    // epilogue: node = m0 + q*4 + r, col = nt*16 + nn15
    float4 dv = *(const float4*)(dinv + m0 + 4 * q);
    const float* dvp = (const float*)&dv;
#pragma unroll
    for (int nt = 0; nt < NT; ++nt) {
#pragma unroll
        for (int r = 0; r < 4; ++r) {
            int node = m0 + q * 4 + r;
            if (node < N_NODES) {
                float val = acc[nt][r] * dvp[r];
                C[(size_t)node * D + nt * 16 + nn15] = f2bf(val);
            }
        }
    }
}

// ---------------- gather, D=128: one wave/node, bf16x2/lane, 8x unroll; bf16 out ----
template <bool RELU>
__global__ void k_gather128(const int* __restrict__ rowptr, const int* __restrict__ col,
                            const float* __restrict__ dinv, const uint32* __restrict__ t,
                            const float* __restrict__ b, uint32* __restrict__ outbuf) {
    unsigned wid = (blockIdx.x * blockDim.x + threadIdx.x) >> 6;
    int lane = threadIdx.x & 63;
    if (wid >= N_NODES) return;
    int beg = rowptr[wid], end = rowptr[wid + 1];
    uint32 p = t[(size_t)wid * 64 + lane];
    float ax = bf_lo(p), ay = bf_hi(p);
    int j = beg;
    for (; j + 8 <= end; j += 8) {
        int s0 = col[j], s1 = col[j+1], s2 = col[j+2], s3 = col[j+3];
        int s4 = col[j+4], s5 = col[j+5], s6 = col[j+6], s7 = col[j+7];
        uint32 v0 = t[(size_t)s0 * 64 + lane];
        uint32 v1 = t[(size_t)s1 * 64 + lane];
        uint32 v2 = t[(size_t)s2 * 64 + lane];
        uint32 v3 = t[(size_t)s3 * 64 + lane];
        uint32 v4 = t[(size_t)s4 * 64 + lane];
        uint32 v5 = t[(size_t)s5 * 64 + lane];
        uint32 v6 = t[(size_t)s6 * 64 + lane];
        uint32 v7 = t[(size_t)s7 * 64 + lane];
        ax += (bf_lo(v0) + bf_lo(v1)) + (bf_lo(v2) + bf_lo(v3))
            + ((bf_lo(v4) + bf_lo(v5)) + (bf_lo(v6) + bf_lo(v7)));
        ay += (bf_hi(v0) + bf_hi(v1)) + (bf_hi(v2) + bf_hi(v3))
            + ((bf_hi(v4) + bf_hi(v5)) + (bf_hi(v6) + bf_hi(v7)));
    }
    for (; j + 4 <= end; j += 4) {
        int s0 = col[j], s1 = col[j+1], s2 = col[j+2], s3 = col[j+3];
        uint32 v0 = t[(size_t)s0 * 64 + lane];
        uint32 v1 = t[(size_t)s1 * 64 + lane];
        uint32 v2 = t[(size_t)s2 * 64 + lane];
        uint32 v3 = t[(size_t)s3 * 64 + lane];
        ax += (bf_lo(v0) + bf_lo(v1)) + (bf_lo(v2) + bf_lo(v3));
        ay += (bf_hi(v0) + bf_hi(v1)) + (bf_hi(v2) + bf_hi(v3));
    }
    for (; j < end; ++j) {
        uint32 v = t[(size_t)col[j] * 64 + lane];
        ax += bf_lo(v); ay += bf_hi(v);
    }
    float di = dinv[wid];
    float2 bb = ((const float2*)b)[lane];
    float ox = di * ax + bb.x;
    float oy = di * ay + bb.y;
    if (RELU) { ox = fmaxf(ox, 0.f); oy = fmaxf(oy, 0.f); }
    outbuf[(size_t)wid * 64 + lane] = (uint32)f2bf(ox) | ((uint32)f2bf(oy) << 16);
}

// ---------------- gather, D=64: bf16 out ----------------
template <bool RELU>
__global__ void k_gather64(const int* __restrict__ rowptr, const int* __restrict__ col,
                           const float* __restrict__ dinv, const ushort16* __restrict__ t,
                           const float* __restrict__ b, ushort16* __restrict__ outbuf) {
    unsigned wid = (blockIdx.x * blockDim.x + threadIdx.x) >> 6;
    int lane = threadIdx.x & 63;
    if (wid >= N_NODES) return;
    int beg = rowptr[wid], end = rowptr[wid + 1];
    float acc = bf2f(t[(size_t)wid * 64 + lane]);
    int j = beg;
    for (; j + 8 <= end; j += 8) {
        int s0 = col[j], s1 = col[j+1], s2 = col[j+2], s3 = col[j+3];
        int s4 = col[j+4], s5 = col[j+5], s6 = col[j+6], s7 = col[j+7];
        float v0 = bf2f(t[(size_t)s0 * 64 + lane]);
        float v1 = bf2f(t[(size_t)s1 * 64 + lane]);
        float v2 = bf2f(t[(size_t)s2 * 64 + lane]);
        float v3 = bf2f(t[(size_t)s3 * 64 + lane]);
        float v4 = bf2f(t[(size_t)s4 * 64 + lane]);
        float v5 = bf2f(t[(size_t)s5 * 64 + lane]);
        float v6 = bf2f(t[(size_t)s6 * 64 + lane]);
        float v7 = bf2f(t[(size_t)s7 * 64 + lane]);
        acc += (v0 + v1) + (v2 + v3) + ((v4 + v5) + (v6 + v7));
    }
    for (; j + 4 <= end; j += 4) {
        int s0 = col[j], s1 = col[j+1], s2 = col[j+2], s3 = col[j+3];
        acc += (bf2f(t[(size_t)s0 * 64 + lane]) + bf2f(t[(size_t)s1 * 64 + lane]))
             + (bf2f(t[(size_t)s2 * 64 + lane]) + bf2f(t[(size_t)s3 * 64 + lane]));
    }
    for (; j < end; ++j) acc += bf2f(t[(size_t)col[j] * 64 + lane]);
    float o = dinv[wid] * acc + b[lane];
    if (RELU) o = fmaxf(o, 0.f);
    outbuf[(size_t)wid * 64 + lane] = f2bf(o);
}

// ---------------- decode: z is bf16 [N x 64] ----------------
__global__ void k_decode(const int* __restrict__ eli, const ushort16* __restrict__ z,
                         float* __restrict__ out) {
    int e = blockIdx.x * blockDim.x + threadIdx.x;
    if (e >= N_EL) return;
    int a = eli[e];
    int b = eli[N_EL + e];
    const uint4* za = (const uint4*)(z + (size_t)a * 64);
    const uint4* zb = (const uint4*)(z + (size_t)b * 64);
    float acc = 0.0f;
#pragma unroll
    for (int i = 0; i < 8; ++i) {
        uint4 va = za[i], vb = zb[i];
        acc += bf_lo(va.x) * bf_lo(vb.x) + bf_hi(va.x) * bf_hi(vb.x);
        acc += bf_lo(va.y) * bf_lo(vb.y) + bf_hi(va.y) * bf_hi(vb.y);
        acc += bf_lo(va.z) * bf_lo(vb.z) + bf_hi(va.z) * bf_hi(vb.z);
        acc += bf_lo(va.w) * bf_lo(vb.w) + bf_hi(va.w) * bf_hi(vb.w);
    }
    out[e] = acc;
}

extern "C" void kernel_launch(void* const* d_in, const int* in_sizes, int n_in,
                              void* d_out, int out_size, void* d_ws, size_t ws_size,
                              hipStream_t stream) {
    const float* x   = (const float*)d_in[0];
    const int*   ei  = (const int*)d_in[1];
    const int*   eli = (const int*)d_in[2];
    const float* W1  = (const float*)d_in[3];
    const float* b1  = (const float*)d_in[4];
    const float* W2  = (const float*)d_in[5];
    const float* b2  = (const float*)d_in[6];
    const float* W3  = (const float*)d_in[7];
    const float* b3  = (const float*)d_in[8];
    float* out = (float*)d_out;

    const int* srcA = ei;
    const int* dstA = ei + N_EDGES;

    // workspace layout (bytes) — non-overlapping:
    //   dinv   [0, 400,000)   rowptr [1M, +400K+4)
    //   bsum [1888K) boff [1896K)   col [2M, 8.4M)   r [9M, 15.4M)
    //   t    [16M, +25.6M)  bf16 N x 128
    //   aggb [48M, +25.6M)  bf16 N x 128 (layers), N x 64 (final z)  -> ends 73.6M
    //   cpad [80M, +6.4M)   line-padded counters (1 int per 64B)
    char* ws = (char*)d_ws;
    float*    dinv   = (float*)   (ws + 0);
    int*      rowptr = (int*)     (ws + (1024u << 10));
    int*      bsum   = (int*)     (ws + (1888u << 10));
    int*      boff   = (int*)     (ws + (1896u << 10));
    int*      col    = (int*)     (ws + (2048u << 10));
    int*      r      = (int*)     (ws + (9u << 20));
    ushort16* t      = (ushort16*)(ws + (16u << 20));
    ushort16* aggb   = (ushort16*)(ws + (48u << 20));
    int*      cpad   = (int*)     (ws + (80u << 20));

    const int B = 256;
    const int gE  = (N_EDGES + B - 1) / B;
    const int gG  = (N_NODES * 64 + B - 1) / B;
    const int gT  = (N_NODES + 63) / 64;      // 1563
    const int gEL = (N_EL + B - 1) / B;

    // ---- CSR build (single atomic pass, padded counters) ----
    hipMemsetAsync(cpad, 0, (size_t)N_NODES * CPAD * sizeof(int), stream);
    k_rank<<<gE, B, 0, stream>>>(dstA, cpad, r);
    k_scan1<<<NB_SCAN, 256, 0, stream>>>(cpad, rowptr, bsum, dinv);
    k_scan2<<<1, 512, 0, stream>>>(bsum, boff);
    k_scan3<<<NB_SCAN, 256, 0, stream>>>(rowptr, boff);
    k_fill2<<<gE, B, 0, stream>>>(srcA, dstA, rowptr, r, col);

    // ---- layer 1 (A = x, f32) ----
    k_gemm_mfma<128, float><<<gT, B, 0, stream>>>(x, W1, dinv, t);
    k_gather128<true><<<gG, B, 0, stream>>>(rowptr, col, dinv, (const uint32*)t, b1,
                                            (uint32*)aggb);
    // ---- layer 2 (A = h1, bf16) ----
    k_gemm_mfma<128, ushort16><<<gT, B, 0, stream>>>(aggb, W2, dinv, t);
    k_gather128<true><<<gG, B, 0, stream>>>(rowptr, col, dinv, (const uint32*)t, b2,
                                            (uint32*)aggb);
    // ---- layer 3 (A = h2, bf16) ----
    k_gemm_mfma<64, ushort16><<<gT, B, 0, stream>>>(aggb, W3, dinv, t);
    k_gather64<false><<<gG, B, 0, stream>>>(rowptr, col, dinv, t, b3, aggb);

    // ---- decode ----
    k_decode<<<gEL, B, 0, stream>>>(eli, aggb, out);
}